// Round 1
// baseline (141.055 us; speedup 1.0000x reference)
//
#include <hip/hip_runtime.h>

#define N_SERIES 1024
#define N_TIME 600
#define INPUT_SIZE 168
#define OUTPUT_SIZE 24
#define N_S 4
#define SEAS 24
#define N_WINDOWS (N_TIME - INPUT_SIZE - OUTPUT_SIZE + 1) /* 409 */
#define SEAS_LEN (N_TIME + SEAS)                          /* 624 */

#define INS_ELEMS (N_WINDOWS * N_SERIES * (INPUT_SIZE + N_S)) /* 72,036,352 */
#define OUTS_ELEMS (N_WINDOWS * N_SERIES * OUTPUT_SIZE)       /* 10,051,584 */
#define LEV_ELEMS (N_SERIES * N_TIME)                         /* 614,400 */
#define SEAS_ELEMS (N_SERIES * SEAS_LEN)                      /* 638,976 */

#define NQ_INS (INS_ELEMS / 4)   /* 18,009,088 */
#define NQ_OUTS (OUTS_ELEMS / 4) /* 2,512,896 */
#define NQ_TOTAL (NQ_INS + NQ_OUTS)

// ---------------------------------------------------------------------------
// Phase 1: sequential exponential-smoothing scan, 1 thread per series.
// Circular seasonal buffer kept in REGISTERS: unrolled in blocks of 24 so the
// buffer index (t % 24) is always a compile-time constant (no scratch spill).
// Identity used: s_t == seasonalities1[:, t]; news_t stored at column t+24.
// ---------------------------------------------------------------------------
__global__ __launch_bounds__(64) void scan_kernel(
    const float* __restrict__ y, const float* __restrict__ embeds,
    const int* __restrict__ idxs, float* __restrict__ levels,
    float* __restrict__ seas1)
{
    int s = blockIdx.x * 64 + threadIdx.x;
    if (s >= N_SERIES) return;
    int row = idxs[s];
    const float* e = embeds + row * (2 + SEAS);
    float lev_sms = 1.0f / (1.0f + __expf(-e[0]));
    float seas_sms = 1.0f / (1.0f + __expf(-e[1]));
    float one_m_lev = 1.0f - lev_sms;
    float one_m_seas = 1.0f - seas_sms;

    const float* yrow = y + s * N_TIME;
    float* lrow = levels + s * N_TIME;
    float* srow = seas1 + s * SEAS_LEN;

    float sb[SEAS];
#pragma unroll
    for (int j = 0; j < SEAS; ++j) {
        float v = __expf(e[2 + j]);
        sb[j] = v;
        srow[j] = v;
    }
    srow[SEAS] = sb[0];

    float lev = yrow[0] / sb[0];
    lrow[0] = lev;

    int t = 1;
    // 24 full blocks of 24 steps: t = 1 .. 576
#pragma unroll 1
    for (int blk = 0; blk < 24; ++blk) {
#pragma unroll
        for (int u = 0; u < 24; ++u) {
            const int k = (u + 1) % 24; // == t % 24 (compile-time)
            float yt = yrow[t];
            float st = sb[k];
            float newlev = lev_sms * (yt / st) + one_m_lev * lev;
            float news = seas_sms * (yt / newlev) + one_m_seas * st;
            lev = newlev;
            sb[k] = news;
            lrow[t] = newlev;
            srow[t + SEAS] = news;
            ++t;
        }
    }
    // tail: t = 577 .. 599 (23 steps); t % 24 == u + 1
#pragma unroll
    for (int u = 0; u < 23; ++u) {
        const int k = u + 1;
        float yt = yrow[t];
        float st = sb[k];
        float newlev = lev_sms * (yt / st) + one_m_lev * lev;
        float news = seas_sms * (yt / newlev) + one_m_seas * st;
        lev = newlev;
        sb[k] = news;
        lrow[t] = newlev;
        srow[t + SEAS] = news;
        ++t;
    }
}

// ---------------------------------------------------------------------------
// Phase 2: windowed outputs, grid-stride over float4s. All reads L2-resident;
// writes coalesced float4. 172 = 168 + 4 and 168 % 4 == 0, so each float4 is
// either fully "insample" or exactly the 4-wide static s_matrix chunk.
// ---------------------------------------------------------------------------
__global__ __launch_bounds__(256) void write_kernel(
    const float* __restrict__ y, const float* __restrict__ s_matrix,
    const float* __restrict__ levels, const float* __restrict__ seas1,
    float4* __restrict__ out_ins, float4* __restrict__ out_outs)
{
    const float LN2 = 0.69314718055994531f;
    int stride = gridDim.x * blockDim.x;
    for (int q = blockIdx.x * blockDim.x + threadIdx.x; q < NQ_TOTAL;
         q += stride) {
        if (q < NQ_INS) {
            int rowq = q / 43;           // (w, s) row index
            int e4 = q - rowq * 43;      // which float4 within the 172 row
            int w = rowq >> 10;
            int s = rowq & 1023;
            float4 v;
            if (e4 == 42) {
                v = *reinterpret_cast<const float4*>(s_matrix + s * N_S);
            } else {
                int t = w + e4 * 4;
                float lev = levels[s * N_TIME + w + INPUT_SIZE - 1];
                const float* yp = y + s * N_TIME + t;
                const float* sp = seas1 + s * SEAS_LEN + t;
                float vv[4];
#pragma unroll
                for (int j = 0; j < 4; ++j) {
                    float r = __fdividef(yp[j], lev * sp[j]);
                    vv[j] = __logf(r);
                }
                v = make_float4(vv[0], vv[1], vv[2], vv[3]);
            }
            out_ins[q] = v;
        } else {
            int q2 = q - NQ_INS;
            int rowq = q2 / 6;
            int j4 = q2 - rowq * 6;
            int w = rowq >> 10;
            int s = rowq & 1023;
            int t = w + INPUT_SIZE + j4 * 4;
            const float* yp = y + s * N_TIME + t;
            out_outs[q2] = make_float4(yp[0], yp[1], yp[2], yp[3]);
        }
    }
    (void)LN2;
}

extern "C" void kernel_launch(void* const* d_in, const int* in_sizes, int n_in,
                              void* d_out, int out_size, void* d_ws, size_t ws_size,
                              hipStream_t stream) {
    const float* y      = (const float*)d_in[0];
    const float* sm     = (const float*)d_in[1];
    const float* embeds = (const float*)d_in[2];
    const int*   idxs   = (const int*)d_in[3];

    float* out      = (float*)d_out;
    float* out_ins  = out;
    float* out_outs = out + INS_ELEMS;
    float* out_lev  = out + INS_ELEMS + OUTS_ELEMS;
    float* out_seas = out_lev + LEV_ELEMS;

    scan_kernel<<<N_SERIES / 64, 64, 0, stream>>>(y, embeds, idxs, out_lev,
                                                  out_seas);
    write_kernel<<<2048, 256, 0, stream>>>(y, sm, out_lev, out_seas,
                                           (float4*)out_ins,
                                           (float4*)out_outs);
}